// Round 1
// baseline (694.730 us; speedup 1.0000x reference)
//
#include <hip/hip_runtime.h>

// out[s, r, c] = in[r, sidx[s] + c]
//   in:  (131072, 512) fp32   (2048*64 rows)
//   out: (16, 131072, 64) fp32
//
// v2: no LDS, no __syncthreads. Each block handles 4 rows per grid-stride
// iteration. Lane layout per wave: j = lane>>4 (row-in-quad), l = lane&15
// (16B column chunk); wave w owns slices 4w..4w+3.
//  - loads: per (wave, slice) the 64 lanes gather the slice's 256B segment
//    from 4 different rows; the 16 slice-streams overlap on the same 4 rows
//    and hit L1 after the first touch (row reuse WITHOUT a barrier).
//  - stores: per (wave, slice) the 64 lanes write 4 consecutive 256B output
//    rows = 1 KB contiguous per store instruction, nontemporal (never read).
// Input gather is only 4B-aligned (sidx is an arbitrary int) -> plain float
// element loads; L1 line-merging keeps HBM fetch at one pass over the rows.

#define ROWS   131072
#define FEATN  512
#define NSLICE 16
#define SLEN   64
#define RPQ    4                 // rows per quad
#define NQUAD  (ROWS / RPQ)      // 32768
#define GRID   2048              // 8 blocks/CU, 16 quads each, no tail

typedef float vfloat4 __attribute__((ext_vector_type(4)));

__global__ __launch_bounds__(256) void fuse_slice_kernel(
    const float* __restrict__ in,
    const int*   __restrict__ sidx,
    float*       __restrict__ out)
{
    const int tid  = threadIdx.x;
    const int wave = tid >> 6;         // 0..3 -> slices 4*wave .. 4*wave+3
    const int lane = tid & 63;
    const int j    = lane >> 4;        // row within quad, 0..3
    const int l4   = (lane & 15) << 2; // column offset 0,4,...,60

    // Per-thread slice starts (wave-uniform, 4 slices per wave), hoisted.
    int start[4];
#pragma unroll
    for (int k = 0; k < 4; ++k) start[k] = sidx[wave * 4 + k] + l4;

    // Output base pointers per slice (row term added in the loop).
    float* outb[4];
#pragma unroll
    for (int k = 0; k < 4; ++k)
        outb[k] = out + ((size_t)(wave * 4 + k) * ROWS) * SLEN + l4;

    for (int q = blockIdx.x; q < NQUAD; q += GRID) {
        const int r = q * RPQ + j;
        const float* inr = in + (size_t)r * FEATN;

        vfloat4 v[4];
#pragma unroll
        for (int k = 0; k < 4; ++k) {
            // 4B-aligned gather; compiler emits dword loads (correct for any
            // sidx). The four slice streams reuse the same row via L1.
            v[k].x = inr[start[k] + 0];
            v[k].y = inr[start[k] + 1];
            v[k].z = inr[start[k] + 2];
            v[k].w = inr[start[k] + 3];
        }

#pragma unroll
        for (int k = 0; k < 4; ++k) {
            // Wave-level: 64 lanes x 16B = 1 KB contiguous per slice.
            vfloat4* outp = reinterpret_cast<vfloat4*>(outb[k] + (size_t)r * SLEN);
            __builtin_nontemporal_store(v[k], outp);
        }
    }
}

extern "C" void kernel_launch(void* const* d_in, const int* in_sizes, int n_in,
                              void* d_out, int out_size, void* d_ws, size_t ws_size,
                              hipStream_t stream)
{
    const float* in   = reinterpret_cast<const float*>(d_in[0]);
    const int*   sidx = reinterpret_cast<const int*>(d_in[1]);
    // d_in[2] = slice_len (64) — fixed by problem shape, baked into SLEN.
    float* out = reinterpret_cast<float*>(d_out);

    fuse_slice_kernel<<<GRID, 256, 0, stream>>>(in, sidx, out);
}